// Round 10
// baseline (185.234 us; speedup 1.0000x reference)
//
#include <hip/hip_runtime.h>

// TripletAngularMarginLoss: bs=16384, d=64 (== number of classes)
// out = mean(relu(0.5 + ap - an)) + mean(relu(0.8-ap)) + mean(relu(an-0.4)) + CE
// ap[i] = min_{t[j]==t[i]} cos(x_i,x_j), an[i] = max_{t[j]!=t[i]} cos(x_i,x_j)
//
// R9 conclusion: T4 counted-vmcnt NULL; five structural theories dead. mine's
// ~105us is invariant to everything EXCEPT the one never-ablated component:
// the shared staging machinery itself. R10 ablation-as-candidate: NO B-staging,
// NO main-loop barriers. B-fragments read per-lane from global (L1/L2-served;
// all 8 blocks/CU share one jspl stream -> lockstep L1 reuse), dist-1 register
// prefetch, 8 waves/SIMD TLP hides latency. LDS holds only the 2KB tjl table.

#define N_ROWS 16384
#define N_DIM 64

typedef __attribute__((ext_vector_type(8))) short bf16x8;
typedef __attribute__((ext_vector_type(4))) float f32x4;

__device__ inline unsigned short f2bf(float f) {
  unsigned u = __float_as_uint(f);
  unsigned r = u + 0x7fffu + ((u >> 16) & 1u);   // round-to-nearest-even
  return (unsigned short)(r >> 16);
}

// order-preserving float->uint encoding for atomicMin/atomicMax
__device__ inline unsigned enc_key(float f) {
  unsigned u = __float_as_uint(f);
  return (u & 0x80000000u) ? ~u : (u | 0x80000000u);
}
__device__ inline float dec_key(unsigned k) {
  unsigned u = (k & 0x80000000u) ? (k ^ 0x80000000u) : ~k;
  return __uint_as_float(u);
}

// ---------------- Kernel A: normalize rows, emit bf16 copy, per-row CE -------
__global__ void prep_kernel(const float* __restrict__ x, const int* __restrict__ tgt,
                            unsigned short* __restrict__ xb, float* __restrict__ ce_row,
                            unsigned* __restrict__ mp_key, unsigned* __restrict__ mn_key,
                            float* __restrict__ out) {
  const int row  = blockIdx.x * 4 + (threadIdx.x >> 6);
  const int lane = threadIdx.x & 63;
  float v  = x[row * N_DIM + lane];
  float ss = v * v;
#pragma unroll
  for (int s = 1; s < 64; s <<= 1) ss += __shfl_xor(ss, s, 64);
  float xn = v * rsqrtf(ss);
  xb[row * N_DIM + lane] = f2bf(xn);

  float mx = xn;
#pragma unroll
  for (int s = 1; s < 64; s <<= 1) mx = fmaxf(mx, __shfl_xor(mx, s, 64));
  float e  = __expf(xn - mx);
  float se = e;
#pragma unroll
  for (int s = 1; s < 64; s <<= 1) se += __shfl_xor(se, s, 64);
  float lse = mx + __logf(se);
  int   t   = tgt[row];                 // wave-uniform
  float xt  = __shfl(xn, t, 64);
  if (lane == 0) {
    ce_row[row] = lse - xt;
    mp_key[row] = 0xFFFFFFFFu;          // +inf key for atomicMin
    mn_key[row] = 0u;                   // -inf key for atomicMax
  }
  if (blockIdx.x == 0 && threadIdx.x == 0) out[0] = 0.f;
}

// ---------------- Kernel B: MFMA similarity + hard mining, stage-free --------
// grid = 128 i-blocks * 16 j-splits = 2048 blocks of 256 threads (4 waves) =
// 8 blocks/CU. Round-robin dispatch: bids {c, c+256, ...} share jspl (256%16==0)
// -> all 8 blocks on a CU stream the SAME B-tiles in rough lockstep (L1 reuse).
// Per jc: lane (m,q) loads col jbase+jc*16+m, dims q*8..q*8+7 (+32) directly
// from global as 2x dwordx4, dist-1 register prefetch, no barriers, no LDS B.
// Tail prefetch (jc=63) reads 2KB past xb -> xb is padded in the workspace.
__global__ __launch_bounds__(256, 8)
void mine_kernel(const unsigned short* __restrict__ xb, const int* __restrict__ tgt,
                 unsigned* __restrict__ mp_key, unsigned* __restrict__ mn_key) {
  __shared__ unsigned short tjl[N_ROWS / 16];  // 2KB: targets of this j-range

  const int lane    = threadIdx.x & 63;
  const int wv      = threadIdx.x >> 6;
  const int iblk    = blockIdx.x >> 4;
  const int jspl    = blockIdx.x & 15;
  const int rowbase = iblk * 128 + wv * 32;
  const int m = lane & 15, q = lane >> 4;
  const int jbase = jspl * (N_ROWS / 16);

  // A fragments: lane holds row (rowbase+tr*16+m), k = q*8..q*8+7 (+32 for ks=1)
  bf16x8 a[2][2];
#pragma unroll
  for (int tr = 0; tr < 2; ++tr) {
    const unsigned short* p = xb + (rowbase + tr * 16 + m) * N_DIM + q * 8;
    a[tr][0] = *(const bf16x8*)(p);
    a[tr][1] = *(const bf16x8*)(p + 32);
  }
  // row targets packed 4x8bit (targets < 64): row = tr*16 + q*4 + r
  unsigned tip[2];
#pragma unroll
  for (int tr = 0; tr < 2; ++tr) {
    unsigned vv = 0;
#pragma unroll
    for (int r = 0; r < 4; ++r)
      vv |= ((unsigned)tgt[rowbase + tr * 16 + q * 4 + r] & 0xffu) << (8 * r);
    tip[tr] = vv;
  }

  float mp[8], mn[8];
#pragma unroll
  for (int k = 0; k < 8; ++k) { mp[k] = __builtin_inff(); mn[k] = -__builtin_inff(); }

  for (int k = threadIdx.x; k < N_ROWS / 16; k += 256)
    tjl[k] = (unsigned short)tgt[jbase + k];
  __syncthreads();                       // tjl ready; no barriers after this

  // direct-global B pointer for this lane; advances 16 cols (2KB) per jc
  const unsigned short* pB = xb + (jbase + m) * N_DIM + q * 8;
  bf16x8 nb0 = *(const bf16x8*)(pB);
  bf16x8 nb1 = *(const bf16x8*)(pB + 32);

#pragma unroll 1
  for (int jc = 0; jc < 64; ++jc) {
    const bf16x8 cb0 = nb0, cb1 = nb1;
    const unsigned ctj = (unsigned)tjl[jc * 16 + m] & 0xffu;
    pB += 16 * N_DIM;                    // prefetch jc+1 (unconditional; padded)
    nb0 = *(const bf16x8*)(pB);
    nb1 = *(const bf16x8*)(pB + 32);

#pragma unroll
    for (int tr = 0; tr < 2; ++tr) {
      f32x4 acc = {0.f, 0.f, 0.f, 0.f};
      acc = __builtin_amdgcn_mfma_f32_16x16x32_bf16(a[tr][0], cb0, acc, 0, 0, 0);
      acc = __builtin_amdgcn_mfma_f32_16x16x32_bf16(a[tr][1], cb1, acc, 0, 0, 0);
#pragma unroll
      for (int r = 0; r < 4; ++r) {
        const bool  pos = (((tip[tr] >> (8 * r)) & 0xffu) == ctj);
        const float d   = acc[r];
        const int   k   = tr * 4 + r;
        mp[k] = fminf(mp[k], pos ? d : __builtin_inff());
        mn[k] = fmaxf(mn[k], pos ? -__builtin_inff() : d);
      }
    }
  }

  // reduce across the 16 lanes (m = 0..15) inside each q-group
#pragma unroll
  for (int s = 1; s < 16; s <<= 1) {
#pragma unroll
    for (int k = 0; k < 8; ++k) {
      mp[k] = fminf(mp[k], __shfl_xor(mp[k], s, 64));
      mn[k] = fmaxf(mn[k], __shfl_xor(mn[k], s, 64));
    }
  }
  if (m == 0) {
#pragma unroll
    for (int tr = 0; tr < 2; ++tr)
#pragma unroll
      for (int r = 0; r < 4; ++r) {
        const int row = rowbase + tr * 16 + q * 4 + r;
        atomicMin(&mp_key[row], enc_key(mp[tr * 4 + r]));
        atomicMax(&mn_key[row], enc_key(mn[tr * 4 + r]));
      }
  }
}

// ---------------- Kernel C: final reduction (8 blocks, float atomicAdd) ------
__global__ void finalize_kernel(const unsigned* __restrict__ mp_key, const unsigned* __restrict__ mn_key,
                                const float* __restrict__ ce_row, float* __restrict__ out) {
  __shared__ float red[16];
  float s = 0.f;
#pragma unroll
  for (int it = 0; it < 2; ++it) {
    const int r = it * 8192 + blockIdx.x * 1024 + threadIdx.x;
    float ap = dec_key(mp_key[r]);
    float an = dec_key(mn_key[r]);
    s += fmaxf(0.5f + ap - an, 0.f) + fmaxf(0.8f - ap, 0.f) +
         fmaxf(an - 0.4f, 0.f) + ce_row[r];
  }
#pragma unroll
  for (int sh = 1; sh < 64; sh <<= 1) s += __shfl_xor(s, sh, 64);
  const int wv = threadIdx.x >> 6;
  if ((threadIdx.x & 63) == 0) red[wv] = s;
  __syncthreads();
  if (threadIdx.x == 0) {
    float t = 0.f;
#pragma unroll
    for (int w = 0; w < 16; ++w) t += red[w];
    atomicAdd(out, t * (1.0f / N_ROWS));
  }
}

extern "C" void kernel_launch(void* const* d_in, const int* in_sizes, int n_in,
                              void* d_out, int out_size, void* d_ws, size_t ws_size,
                              hipStream_t stream) {
  const float* x   = (const float*)d_in[0];
  const int*   tgt = (const int*)d_in[1];
  char* ws = (char*)d_ws;

  // xb gets a 4KB pad (tail prefetch reads <=2KB past the 2MB array)
  unsigned short* xb     = (unsigned short*)ws;                                  // 2 MB + pad
  unsigned*       mp_key = (unsigned*)(ws + (2u << 20) + (4u << 10));            // 64 KB
  unsigned*       mn_key = (unsigned*)(ws + (2u << 20) + (4u << 10) + (64u << 10));
  float*          ce_row = (float*)(ws + (2u << 20) + (4u << 10) + (128u << 10));
  float*          out    = (float*)d_out;

  prep_kernel<<<N_ROWS / 4, 256, 0, stream>>>(x, tgt, xb, ce_row, mp_key, mn_key, out);
  mine_kernel<<<(N_ROWS / 128) * 16, 256, 0, stream>>>(xb, tgt, mp_key, mn_key);
  finalize_kernel<<<8, 1024, 0, stream>>>(mp_key, mn_key, ce_row, out);
}